// Round 1
// baseline (330.595 us; speedup 1.0000x reference)
//
#include <hip/hip_runtime.h>
#include <math.h>

#define SEQ  8192
#define DIN  768
#define DOUT 64

// ---------------------------------------------------------------------------
// Kernel A: QKV projection.  grid (SEQ/64, 3), block 256.
//   mat 0 -> Q^T [DOUT][SEQ], pre-scaled by 1/sqrt(DOUT)=0.125
//   mat 1 -> K^T [DOUT][SEQ]
//   mat 2 -> V   [SEQ][DOUT]
// ---------------------------------------------------------------------------
#define TK 16

__global__ __launch_bounds__(256) void qkv_kernel(
    const float* __restrict__ x,
    const float* __restrict__ Wq,
    const float* __restrict__ Wk,
    const float* __restrict__ Wv,
    float* __restrict__ qkv)
{
    const int mat  = blockIdx.y;
    const float* W = (mat == 0) ? Wq : (mat == 1) ? Wk : Wv;
    const int row0 = blockIdx.x * 64;
    const int t    = threadIdx.x;

    __shared__ float xs[64][TK + 1];     // [row][k]  pad 17: reads 2-way max
    __shared__ float wst[TK][DOUT + 4];  // [k][col]  pad 68: aligned b128, bcast reads

    const int r  = t & 63;        // output row within tile
    const int cg = t >> 6;        // 0..3
    const int c0 = cg * 16;       // 16 cols per thread

    float acc[16];
#pragma unroll
    for (int i = 0; i < 16; ++i) acc[i] = 0.f;

    for (int k0 = 0; k0 < DIN; k0 += TK) {
        // stage x tile: 64x16 floats as 256 float4 (one per thread)
        {
            const int i  = t >> 2;   // row 0..63
            const int jc = t & 3;    // float4 within k-chunk
            const float4 xv = *reinterpret_cast<const float4*>(
                &x[(size_t)(row0 + i) * DIN + k0 + 4 * jc]);
            xs[i][4 * jc + 0] = xv.x;
            xs[i][4 * jc + 1] = xv.y;
            xs[i][4 * jc + 2] = xv.z;
            xs[i][4 * jc + 3] = xv.w;

            // stage W tile transposed: W[c][k0+4jc..] -> wst[j][c]
            const int c = t >> 2;    // 0..63
            const float4 wv = *reinterpret_cast<const float4*>(
                &W[(size_t)c * DIN + k0 + 4 * jc]);
            wst[4 * jc + 0][c] = wv.x;
            wst[4 * jc + 1][c] = wv.y;
            wst[4 * jc + 2][c] = wv.z;
            wst[4 * jc + 3][c] = wv.w;
        }
        __syncthreads();

#pragma unroll
        for (int j = 0; j < TK; ++j) {
            const float xv = xs[r][j];
            const float4 w0 = *reinterpret_cast<const float4*>(&wst[j][c0 + 0]);
            const float4 w1 = *reinterpret_cast<const float4*>(&wst[j][c0 + 4]);
            const float4 w2 = *reinterpret_cast<const float4*>(&wst[j][c0 + 8]);
            const float4 w3 = *reinterpret_cast<const float4*>(&wst[j][c0 + 12]);
            acc[0]  = fmaf(xv, w0.x, acc[0]);
            acc[1]  = fmaf(xv, w0.y, acc[1]);
            acc[2]  = fmaf(xv, w0.z, acc[2]);
            acc[3]  = fmaf(xv, w0.w, acc[3]);
            acc[4]  = fmaf(xv, w1.x, acc[4]);
            acc[5]  = fmaf(xv, w1.y, acc[5]);
            acc[6]  = fmaf(xv, w1.z, acc[6]);
            acc[7]  = fmaf(xv, w1.w, acc[7]);
            acc[8]  = fmaf(xv, w2.x, acc[8]);
            acc[9]  = fmaf(xv, w2.y, acc[9]);
            acc[10] = fmaf(xv, w2.z, acc[10]);
            acc[11] = fmaf(xv, w2.w, acc[11]);
            acc[12] = fmaf(xv, w3.x, acc[12]);
            acc[13] = fmaf(xv, w3.y, acc[13]);
            acc[14] = fmaf(xv, w3.z, acc[14]);
            acc[15] = fmaf(xv, w3.w, acc[15]);
        }
        __syncthreads();
    }

    float* Q_T = qkv;                                // [DOUT][SEQ]
    float* K_T = qkv + (size_t)SEQ * DOUT;           // [DOUT][SEQ]
    float* V   = qkv + (size_t)2 * SEQ * DOUT;       // [SEQ][DOUT]

    if (mat == 2) {
#pragma unroll
        for (int cc = 0; cc < 16; cc += 4) {
            float4 v4 = make_float4(acc[cc], acc[cc + 1], acc[cc + 2], acc[cc + 3]);
            *reinterpret_cast<float4*>(&V[(size_t)(row0 + r) * DOUT + c0 + cc]) = v4;
        }
    } else {
        float* outp   = (mat == 0) ? Q_T : K_T;
        const float s = (mat == 0) ? 0.125f : 1.0f;
#pragma unroll
        for (int cc = 0; cc < 16; ++cc)
            outp[(size_t)(c0 + cc) * SEQ + row0 + r] = acc[cc] * s;
    }
}

// ---------------------------------------------------------------------------
// Kernel B: flash attention, fp32.  grid (SEQ/BM, nsplit), block 256.
// Each block: BM=64 q-rows, iterates its K-chunk in BN=64 tiles.
// Thread (tx=t&15, ty=t>>4) owns rows 4ty..4ty+3 x cols 4tx..4tx+3.
// Writes unnormalized O + (m,l) per row per split (or normalized direct out).
// ---------------------------------------------------------------------------
#define BM 64
#define BN 64

__global__ __launch_bounds__(256, 2) void flash_kernel(
    const float* __restrict__ qkv,
    float* __restrict__ opart,   // [nsplit][SEQ][DOUT]  (== out when direct)
    float* __restrict__ ml,      // [nsplit][SEQ][2]
    int nsplit, int direct)
{
    const float* Q_T = qkv;
    const float* K_T = qkv + (size_t)SEQ * DOUT;
    const float* V   = qkv + (size_t)2 * SEQ * DOUT;

    const int row0  = blockIdx.x * BM;
    const int split = blockIdx.y;
    const int chunk = SEQ / nsplit;
    const int kbeg  = split * chunk;
    const int kend  = kbeg + chunk;

    __shared__ float qs[DOUT][BM + 4];   // [d][r]  pad 68 (16B aligned)
    __shared__ float ks[DOUT][BN + 4];   // [d][c]
    __shared__ float vs[BN][DOUT + 8];   // [c][d]  pad 72
    __shared__ float ps[BN][BM + 4];     // [c][r]

    const int t  = threadIdx.x;
    const int tx = t & 15;
    const int ty = t >> 4;
    const int r0 = 4 * ty;
    const int c0 = 4 * tx;

    // stage Q tile once: qs[d][r] from Q_T[d][row0+r]
#pragma unroll
    for (int l = 0; l < 4; ++l) {
        const int idx = t + 256 * l;      // 0..1023
        const int d   = idx >> 4;
        const int rc  = idx & 15;
        const float4 qv = *reinterpret_cast<const float4*>(
            &Q_T[(size_t)d * SEQ + row0 + 4 * rc]);
        *reinterpret_cast<float4*>(&qs[d][4 * rc]) = qv;
    }

    float o[16];
    float m_run[4], l_run[4];
#pragma unroll
    for (int i = 0; i < 16; ++i) o[i] = 0.f;
#pragma unroll
    for (int i = 0; i < 4; ++i) { m_run[i] = -INFINITY; l_run[i] = 0.f; }

    for (int kt = kbeg; kt < kend; kt += BN) {
        __syncthreads();   // previous tile's vs/ps reads complete
        // stage K tile (transposed source) and V tile
#pragma unroll
        for (int l = 0; l < 4; ++l) {
            const int idx = t + 256 * l;
            const int d   = idx >> 4;     // also used as c for V
            const int rc  = idx & 15;
            const float4 kv = *reinterpret_cast<const float4*>(
                &K_T[(size_t)d * SEQ + kt + 4 * rc]);
            *reinterpret_cast<float4*>(&ks[d][4 * rc]) = kv;
            const float4 vv = *reinterpret_cast<const float4*>(
                &V[(size_t)(kt + d) * DOUT + 4 * rc]);
            *reinterpret_cast<float4*>(&vs[d][4 * rc]) = vv;
        }
        __syncthreads();

        // ---- S = (Q/8) K^T tile: s[i][j], rows r0+i, cols c0+j ----
        float s[16];
#pragma unroll
        for (int i = 0; i < 16; ++i) s[i] = 0.f;

#pragma unroll 4
        for (int d = 0; d < 64; ++d) {
            const float4 qv = *reinterpret_cast<const float4*>(&qs[d][r0]);
            const float4 kv = *reinterpret_cast<const float4*>(&ks[d][c0]);
            const float qa[4] = {qv.x, qv.y, qv.z, qv.w};
            const float ka[4] = {kv.x, kv.y, kv.z, kv.w};
#pragma unroll
            for (int i = 0; i < 4; ++i)
#pragma unroll
                for (int j = 0; j < 4; ++j)
                    s[i * 4 + j] = fmaf(qa[i], ka[j], s[i * 4 + j]);
        }

        // ---- online softmax ----
        float mt[4];
#pragma unroll
        for (int i = 0; i < 4; ++i)
            mt[i] = fmaxf(fmaxf(s[i * 4], s[i * 4 + 1]),
                          fmaxf(s[i * 4 + 2], s[i * 4 + 3]));
#pragma unroll
        for (int off = 1; off < 16; off <<= 1)
#pragma unroll
            for (int i = 0; i < 4; ++i)
                mt[i] = fmaxf(mt[i], __shfl_xor(mt[i], off, 64));

        float alpha[4];
#pragma unroll
        for (int i = 0; i < 4; ++i) {
            const float mn = fmaxf(m_run[i], mt[i]);
            alpha[i] = __expf(m_run[i] - mn);
            m_run[i] = mn;
        }

        float p[16], lt[4];
#pragma unroll
        for (int i = 0; i < 4; ++i) {
            lt[i] = 0.f;
#pragma unroll
            for (int j = 0; j < 4; ++j) {
                p[i * 4 + j] = __expf(s[i * 4 + j] - m_run[i]);
                lt[i] += p[i * 4 + j];
            }
        }
#pragma unroll
        for (int off = 1; off < 16; off <<= 1)
#pragma unroll
            for (int i = 0; i < 4; ++i)
                lt[i] += __shfl_xor(lt[i], off, 64);

#pragma unroll
        for (int i = 0; i < 4; ++i) {
            l_run[i] = l_run[i] * alpha[i] + lt[i];
#pragma unroll
            for (int j = 0; j < 4; ++j)
                o[i * 4 + j] *= alpha[i];
        }

        // write P transposed: ps[c0+j][r0..r0+3]
#pragma unroll
        for (int j = 0; j < 4; ++j) {
            float4 pj = make_float4(p[j], p[4 + j], p[8 + j], p[12 + j]);
            *reinterpret_cast<float4*>(&ps[c0 + j][r0]) = pj;
        }
        __syncthreads();

        // ---- O += P V tile ----
#pragma unroll 4
        for (int c = 0; c < 64; ++c) {
            const float4 pv = *reinterpret_cast<const float4*>(&ps[c][r0]);
            const float4 vv = *reinterpret_cast<const float4*>(&vs[c][c0]);
            const float pa[4] = {pv.x, pv.y, pv.z, pv.w};
            const float va[4] = {vv.x, vv.y, vv.z, vv.w};
#pragma unroll
            for (int i = 0; i < 4; ++i)
#pragma unroll
                for (int j = 0; j < 4; ++j)
                    o[i * 4 + j] = fmaf(pa[i], va[j], o[i * 4 + j]);
        }
    }

    // ---- epilogue ----
    if (direct) {
#pragma unroll
        for (int i = 0; i < 4; ++i) {
            const float inv = 1.0f / l_run[i];
            float4 v4 = make_float4(o[i * 4] * inv, o[i * 4 + 1] * inv,
                                    o[i * 4 + 2] * inv, o[i * 4 + 3] * inv);
            *reinterpret_cast<float4*>(
                &opart[(size_t)(row0 + r0 + i) * DOUT + c0]) = v4;
        }
    } else {
#pragma unroll
        for (int i = 0; i < 4; ++i) {
            float4 v4 = make_float4(o[i * 4], o[i * 4 + 1],
                                    o[i * 4 + 2], o[i * 4 + 3]);
            *reinterpret_cast<float4*>(
                &opart[((size_t)split * SEQ + row0 + r0 + i) * DOUT + c0]) = v4;
        }
        if (tx == 0) {
#pragma unroll
            for (int i = 0; i < 4; ++i) {
                const size_t mrow = (size_t)split * SEQ + row0 + r0 + i;
                ml[mrow * 2 + 0] = m_run[i];
                ml[mrow * 2 + 1] = l_run[i];
            }
        }
    }
}

// ---------------------------------------------------------------------------
// Kernel C: combine split partials (log-sum-exp merge)
// ---------------------------------------------------------------------------
__global__ __launch_bounds__(256) void combine_kernel(
    const float* __restrict__ opart,
    const float* __restrict__ ml,
    float* __restrict__ out, int nsplit)
{
    const int idx = blockIdx.x * 256 + threadIdx.x;
    if (idx >= SEQ * DOUT) return;
    const int row = idx >> 6;

    float M = -INFINITY;
    for (int s = 0; s < nsplit; ++s)
        M = fmaxf(M, ml[((size_t)s * SEQ + row) * 2]);

    float denom = 0.f, acc = 0.f;
    for (int s = 0; s < nsplit; ++s) {
        const float w = __expf(ml[((size_t)s * SEQ + row) * 2] - M);
        denom += ml[((size_t)s * SEQ + row) * 2 + 1] * w;
        acc   += opart[(size_t)s * SEQ * DOUT + idx] * w;
    }
    out[idx] = acc / denom;
}

// ---------------------------------------------------------------------------
extern "C" void kernel_launch(void* const* d_in, const int* in_sizes, int n_in,
                              void* d_out, int out_size, void* d_ws, size_t ws_size,
                              hipStream_t stream)
{
    const float* x  = (const float*)d_in[0];
    const float* Wq = (const float*)d_in[1];
    const float* Wk = (const float*)d_in[2];
    const float* Wv = (const float*)d_in[3];
    float* out = (float*)d_out;
    float* ws  = (float*)d_ws;

    const size_t qkv_elems = (size_t)3 * SEQ * DOUT;

    int nsplit = 4;
    size_t need4 = (qkv_elems + (size_t)nsplit * SEQ * DOUT +
                    (size_t)nsplit * SEQ * 2) * sizeof(float);
    const int direct = (ws_size < need4);
    if (direct) nsplit = 1;

    qkv_kernel<<<dim3(SEQ / 64, 3), 256, 0, stream>>>(x, Wq, Wk, Wv, ws);

    if (direct) {
        flash_kernel<<<dim3(SEQ / BM, 1), 256, 0, stream>>>(ws, out, nullptr, 1, 1);
    } else {
        float* opart = ws + qkv_elems;
        float* mlp   = opart + (size_t)nsplit * SEQ * DOUT;
        flash_kernel<<<dim3(SEQ / BM, nsplit), 256, 0, stream>>>(ws, opart, mlp, nsplit, 0);
        combine_kernel<<<(SEQ * DOUT + 255) / 256, 256, 0, stream>>>(opart, mlp, out, nsplit);
    }
}

// Round 2
// 98.719 us; speedup vs baseline: 3.3489x; 3.3489x over previous
//
#include <hip/hip_runtime.h>
#include <hip/hip_bf16.h>
#include <math.h>

#define SEQ 8192
#define DIN 768
#define DOUT 64

typedef __attribute__((ext_vector_type(8))) short short8;
typedef __attribute__((ext_vector_type(4))) float floatx4;

// ---------------------------------------------------------------------------
// helpers
// ---------------------------------------------------------------------------
__device__ __forceinline__ void gload16(const void* g, void* l) {
    __builtin_amdgcn_global_load_lds(
        (const __attribute__((address_space(1))) unsigned int*)g,
        (__attribute__((address_space(3))) unsigned int*)l, 16, 0, 0);
}

__device__ __forceinline__ unsigned pack2(float a, float b) {
    __hip_bfloat162 h = __float22bfloat162_rn(make_float2(a, b));
    return *(unsigned*)&h;
}

__device__ __forceinline__ unsigned short bfbits(float f) {
    __hip_bfloat16 h = __float2bfloat16(f);
    return *(unsigned short*)&h;
}

// ---------------------------------------------------------------------------
// Kernel 0: W (3 x [64][768] fp32) -> wbf [192][768] bf16 row-major
// ---------------------------------------------------------------------------
__global__ __launch_bounds__(256) void prep_w(
    const float* __restrict__ Wq, const float* __restrict__ Wk,
    const float* __restrict__ Wv, unsigned short* __restrict__ wbf)
{
    const int i = blockIdx.x * 256 + threadIdx.x;   // 0..18431
    const int base = i * 8;                          // 8 elems per thread
    const int row = base / DIN;                      // 0..191
    const int k = base % DIN;
    const float* src = (row < 64)  ? &Wq[(size_t)row * DIN + k]
                     : (row < 128) ? &Wk[(size_t)(row - 64) * DIN + k]
                                   : &Wv[(size_t)(row - 128) * DIN + k];
    const float4 f0 = *(const float4*)src;
    const float4 f1 = *(const float4*)(src + 4);
    uint4 v;
    v.x = pack2(f0.x, f0.y);
    v.y = pack2(f0.z, f0.w);
    v.z = pack2(f1.x, f1.y);
    v.w = pack2(f1.z, f1.w);
    *(uint4*)&wbf[base] = v;
}

// ---------------------------------------------------------------------------
// Kernel 1: QKV projection via MFMA.  grid 128 blocks x 256 thr (4 waves).
// Out: qbf [SEQ][64] bf16 (pre-scaled 0.125), kbf [SEQ][64], vtbf [64][SEQ].
// LDS tiles swizzled: byte(R,c) = R*128 + (((c>>3) ^ (R&7))<<4) + (c&7)*2
// ---------------------------------------------------------------------------
__global__ __launch_bounds__(256) void qkv_mfma(
    const float* __restrict__ x, const unsigned short* __restrict__ wbf,
    unsigned short* __restrict__ qbf, unsigned short* __restrict__ kbf,
    unsigned short* __restrict__ vtbf)
{
    __shared__ __align__(16) unsigned char xs[64 * 128];    // [64 rows][64 k] bf16
    __shared__ __align__(16) unsigned char wsm[192 * 128];  // [192 n][64 k] bf16

    const int t = threadIdx.x;
    const int l = t & 63;
    const int wid = t >> 6;
    const int row0 = blockIdx.x * 64;

    floatx4 acc[12];
#pragma unroll
    for (int i = 0; i < 12; ++i) acc[i] = (floatx4){0.f, 0.f, 0.f, 0.f};

    for (int kc = 0; kc < 12; ++kc) {
        const int k0 = kc * 64;
        __syncthreads();   // previous chunk's reads done

        // stage x tile (fp32 -> bf16, swizzled ds_write_b128)
        {
            const int R = t >> 2;            // 0..63
#pragma unroll
            for (int ss = 0; ss < 2; ++ss) {
                const int slot = (t & 3) * 2 + ss;   // 0..7
                const float4 a = *(const float4*)&x[(size_t)(row0 + R) * DIN + k0 + slot * 8];
                const float4 b = *(const float4*)&x[(size_t)(row0 + R) * DIN + k0 + slot * 8 + 4];
                uint4 v;
                v.x = pack2(a.x, a.y);
                v.y = pack2(a.z, a.w);
                v.z = pack2(b.x, b.y);
                v.w = pack2(b.z, b.w);
                *(uint4*)&xs[R * 128 + ((slot ^ (R & 7)) << 4)] = v;
            }
        }
        // stage W tile via global_load_lds (pre-swizzled source)
#pragma unroll
        for (int ss = 0; ss < 6; ++ss) {
            const int s = wid * 6 + ss;              // 0..23
            const int R = 8 * s + (l >> 3);          // 0..191
            const int slot = (l & 7) ^ (l >> 3);
            gload16(&wbf[(size_t)R * DIN + k0 + slot * 8], &wsm[s * 1024]);
        }
        __syncthreads();

#pragma unroll
        for (int ks = 0; ks < 2; ++ks) {
            const int Rq = wid * 16 + (l & 15);
            const int slot = (l >> 4) + 4 * ks;
            const short8 a = *(const short8*)&xs[Rq * 128 + ((slot ^ (Rq & 7)) << 4)];
#pragma unroll
            for (int nt = 0; nt < 12; ++nt) {
                const int Rw = nt * 16 + (l & 15);
                const short8 b = *(const short8*)&wsm[Rw * 128 + ((slot ^ (Rw & 7)) << 4)];
                acc[nt] = __builtin_amdgcn_mfma_f32_16x16x32_bf16(a, b, acc[nt], 0, 0, 0);
            }
        }
    }

    // epilogue: C layout row=(l>>4)*4+reg, col=l&15
    const int rb = row0 + wid * 16 + ((l >> 4) << 2);
#pragma unroll
    for (int nt = 0; nt < 12; ++nt) {
#pragma unroll
        for (int r = 0; r < 4; ++r) {
            const float v = acc[nt][r];
            const int R = rb + r;
            if (nt < 4) {
                qbf[(size_t)R * 64 + nt * 16 + (l & 15)] = bfbits(v * 0.125f);
            } else if (nt < 8) {
                kbf[(size_t)R * 64 + (nt - 4) * 16 + (l & 15)] = bfbits(v);
            } else {
                vtbf[(size_t)((nt - 8) * 16 + (l & 15)) * SEQ + R] = bfbits(v);
            }
        }
    }
}

// ---------------------------------------------------------------------------
// Kernel 2: flash attention via MFMA.  grid (SEQ/64, nsplit), 256 thr.
// Q pre-scaled.  Per wave: 16 Q-rows.  K-tile = 64 keys, dbuf LDS.
// ---------------------------------------------------------------------------
__global__ __launch_bounds__(256) void flash_mfma(
    const unsigned short* __restrict__ qbf,
    const unsigned short* __restrict__ kbf,
    const unsigned short* __restrict__ vtbf,
    float* __restrict__ opart,   // [nsplit][SEQ][64] (== out when direct)
    float* __restrict__ ml,      // [nsplit][SEQ][2]
    int nsplit, int direct)
{
    __shared__ __align__(16) unsigned char lq[64 * 128];
    __shared__ __align__(16) unsigned char lk[2][64 * 128];
    __shared__ __align__(16) unsigned char lv[2][64 * 128];
    __shared__ __align__(16) unsigned char lp[64 * 128];

    const int t = threadIdx.x;
    const int l = t & 63;
    const int wid = t >> 6;
    const int row0 = blockIdx.x * 64;
    const int split = blockIdx.y;
    const int chunk = SEQ / nsplit;
    const int kbeg = split * chunk;
    const int NT = chunk / 64;

    // prologue: stage Q + K0 + V0
    {
        const int Rr = l >> 3;
        const int slot = (l & 7) ^ Rr;
#pragma unroll
        for (int ss = 0; ss < 2; ++ss) {
            const int s = wid * 2 + ss;
            const int R = 8 * s + Rr;
            gload16(&qbf[(size_t)(row0 + R) * 64 + slot * 8], &lq[s * 1024]);
            gload16(&kbf[(size_t)(kbeg + R) * 64 + slot * 8], &lk[0][s * 1024]);
            gload16(&vtbf[(size_t)R * SEQ + kbeg + slot * 8], &lv[0][s * 1024]);
        }
    }
    __syncthreads();

    // Q fragments to registers (reused whole loop)
    short8 qf[2];
#pragma unroll
    for (int ks = 0; ks < 2; ++ks) {
        const int R = wid * 16 + (l & 15);
        const int slot = (l >> 4) + 4 * ks;
        qf[ks] = *(const short8*)&lq[R * 128 + ((slot ^ (R & 7)) << 4)];
    }

    floatx4 oacc[4];
    float m_run[4], l_run[4];
#pragma unroll
    for (int i = 0; i < 4; ++i) {
        oacc[i] = (floatx4){0.f, 0.f, 0.f, 0.f};
        m_run[i] = -INFINITY;
        l_run[i] = 0.f;
    }

    int cur = 0;
    for (int tt = 0; tt < NT; ++tt) {
        // prefetch next K/V tile into buf[cur^1]
        if (tt + 1 < NT) {
            const int kt1 = kbeg + (tt + 1) * 64;
            const int Rr = l >> 3;
            const int slot = (l & 7) ^ Rr;
#pragma unroll
            for (int ss = 0; ss < 2; ++ss) {
                const int s = wid * 2 + ss;
                const int R = 8 * s + Rr;
                gload16(&kbf[(size_t)(kt1 + R) * 64 + slot * 8], &lk[cur ^ 1][s * 1024]);
                gload16(&vtbf[(size_t)R * SEQ + kt1 + slot * 8], &lv[cur ^ 1][s * 1024]);
            }
        }

        // ---- S = Q K^T (Q pre-scaled) ----
        floatx4 sacc[4];
#pragma unroll
        for (int i = 0; i < 4; ++i) sacc[i] = (floatx4){0.f, 0.f, 0.f, 0.f};
#pragma unroll
        for (int ks = 0; ks < 2; ++ks) {
            const int slot = (l >> 4) + 4 * ks;
#pragma unroll
            for (int nt = 0; nt < 4; ++nt) {
                const int R = nt * 16 + (l & 15);
                const short8 b = *(const short8*)&lk[cur][R * 128 + ((slot ^ (R & 7)) << 4)];
                sacc[nt] = __builtin_amdgcn_mfma_f32_16x16x32_bf16(qf[ks], b, sacc[nt], 0, 0, 0);
            }
        }

        // ---- online softmax (rows = (l>>4)*4+r, cols = lanes&15 across nt) ----
        float mt[4];
#pragma unroll
        for (int r = 0; r < 4; ++r)
            mt[r] = fmaxf(fmaxf(sacc[0][r], sacc[1][r]), fmaxf(sacc[2][r], sacc[3][r]));
#pragma unroll
        for (int off = 1; off < 16; off <<= 1)
#pragma unroll
            for (int r = 0; r < 4; ++r)
                mt[r] = fmaxf(mt[r], __shfl_xor(mt[r], off));

        float alpha[4];
#pragma unroll
        for (int r = 0; r < 4; ++r) {
            const float mn = fmaxf(m_run[r], mt[r]);
            alpha[r] = __expf(m_run[r] - mn);
            m_run[r] = mn;
        }

        float p[4][4], lt[4];
#pragma unroll
        for (int r = 0; r < 4; ++r) lt[r] = 0.f;
#pragma unroll
        for (int nt = 0; nt < 4; ++nt)
#pragma unroll
            for (int r = 0; r < 4; ++r) {
                p[nt][r] = __expf(sacc[nt][r] - m_run[r]);
                lt[r] += p[nt][r];
            }
#pragma unroll
        for (int off = 1; off < 16; off <<= 1)
#pragma unroll
            for (int r = 0; r < 4; ++r)
                lt[r] += __shfl_xor(lt[r], off);

#pragma unroll
        for (int r = 0; r < 4; ++r) {
            l_run[r] = l_run[r] * alpha[r] + lt[r];
#pragma unroll
            for (int nt = 0; nt < 4; ++nt) oacc[nt][r] *= alpha[r];
        }

        // ---- P -> LDS (bf16, swizzled; own-wave strip only) ----
#pragma unroll
        for (int nt = 0; nt < 4; ++nt)
#pragma unroll
            for (int r = 0; r < 4; ++r) {
                const int R = wid * 16 + ((l >> 4) << 2) + r;
                const int c = nt * 16 + (l & 15);
                const int slot = c >> 3;
                *(unsigned short*)&lp[R * 128 + ((slot ^ (R & 7)) << 4) + (c & 7) * 2] =
                    bfbits(p[nt][r]);
            }

        // ---- O += P V ----
        short8 pf[2];
#pragma unroll
        for (int ks = 0; ks < 2; ++ks) {
            const int R = wid * 16 + (l & 15);
            const int slot = (l >> 4) + 4 * ks;
            pf[ks] = *(const short8*)&lp[R * 128 + ((slot ^ (R & 7)) << 4)];
        }
#pragma unroll
        for (int ks = 0; ks < 2; ++ks) {
            const int slot = (l >> 4) + 4 * ks;
#pragma unroll
            for (int nt = 0; nt < 4; ++nt) {
                const int R = nt * 16 + (l & 15);
                const short8 b = *(const short8*)&lv[cur][R * 128 + ((slot ^ (R & 7)) << 4)];
                oacc[nt] = __builtin_amdgcn_mfma_f32_16x16x32_bf16(pf[ks], b, oacc[nt], 0, 0, 0);
            }
        }

        __syncthreads();   // prefetch complete (vmcnt drained) + all waves done with buf[cur]
        cur ^= 1;
    }

    // ---- epilogue ----
    const int rb = wid * 16 + ((l >> 4) << 2);
    if (direct) {
#pragma unroll
        for (int r = 0; r < 4; ++r) {
            const float inv = 1.0f / l_run[r];
#pragma unroll
            for (int nt = 0; nt < 4; ++nt)
                opart[(size_t)(row0 + rb + r) * 64 + nt * 16 + (l & 15)] = oacc[nt][r] * inv;
        }
    } else {
#pragma unroll
        for (int r = 0; r < 4; ++r)
#pragma unroll
            for (int nt = 0; nt < 4; ++nt)
                opart[((size_t)split * SEQ + row0 + rb + r) * 64 + nt * 16 + (l & 15)] = oacc[nt][r];
        if ((l & 15) == 0) {
#pragma unroll
            for (int r = 0; r < 4; ++r) {
                const size_t mrow = (size_t)split * SEQ + row0 + rb + r;
                ml[mrow * 2 + 0] = m_run[r];
                ml[mrow * 2 + 1] = l_run[r];
            }
        }
    }
}

// ---------------------------------------------------------------------------
// Kernel 3: combine split partials (log-sum-exp merge)
// ---------------------------------------------------------------------------
__global__ __launch_bounds__(256) void combine_kernel(
    const float* __restrict__ opart, const float* __restrict__ ml,
    float* __restrict__ out, int nsplit)
{
    const int idx = blockIdx.x * 256 + threadIdx.x;
    if (idx >= SEQ * DOUT) return;
    const int row = idx >> 6;

    float M = -INFINITY;
    for (int s = 0; s < nsplit; ++s)
        M = fmaxf(M, ml[((size_t)s * SEQ + row) * 2]);

    float denom = 0.f, acc = 0.f;
    for (int s = 0; s < nsplit; ++s) {
        const float w = __expf(ml[((size_t)s * SEQ + row) * 2] - M);
        denom += ml[((size_t)s * SEQ + row) * 2 + 1] * w;
        acc += opart[(size_t)s * SEQ * DOUT + idx] * w;
    }
    out[idx] = acc / denom;
}

// ---------------------------------------------------------------------------
extern "C" void kernel_launch(void* const* d_in, const int* in_sizes, int n_in,
                              void* d_out, int out_size, void* d_ws, size_t ws_size,
                              hipStream_t stream)
{
    const float* x  = (const float*)d_in[0];
    const float* Wq = (const float*)d_in[1];
    const float* Wk = (const float*)d_in[2];
    const float* Wv = (const float*)d_in[3];
    float* out = (float*)d_out;
    unsigned char* ws = (unsigned char*)d_ws;

    // workspace layout (bytes)
    const size_t wbf_b  = (size_t)192 * DIN * 2;         // 294912
    const size_t qkv_b  = (size_t)SEQ * 64 * 2;          // 1 MB each
    size_t off = 0;
    unsigned short* wbf  = (unsigned short*)(ws + off); off += wbf_b;
    unsigned short* qbf  = (unsigned short*)(ws + off); off += qkv_b;
    unsigned short* kbf  = (unsigned short*)(ws + off); off += qkv_b;
    unsigned short* vtbf = (unsigned short*)(ws + off); off += qkv_b;

    int nsplit = 4;
    const size_t opart_b = (size_t)nsplit * SEQ * 64 * 4;
    const size_t ml_b    = (size_t)nsplit * SEQ * 2 * 4;
    const int direct = (ws_size < off + opart_b + ml_b);
    if (direct) nsplit = 1;

    prep_w<<<72, 256, 0, stream>>>(Wq, Wk, Wv, wbf);
    qkv_mfma<<<SEQ / 64, 256, 0, stream>>>(x, wbf, qbf, kbf, vtbf);

    if (direct) {
        flash_mfma<<<dim3(SEQ / 64, 1), 256, 0, stream>>>(
            qbf, kbf, vtbf, out, nullptr, 1, 1);
    } else {
        float* opart = (float*)(ws + off);
        float* mlp   = (float*)(ws + off + opart_b);
        flash_mfma<<<dim3(SEQ / 64, nsplit), 256, 0, stream>>>(
            qbf, kbf, vtbf, opart, mlp, nsplit, 0);
        combine_kernel<<<(SEQ * DOUT + 255) / 256, 256, 0, stream>>>(opart, mlp, out, nsplit);
    }
}

// Round 3
// 79.078 us; speedup vs baseline: 4.1806x; 1.2484x over previous
//
#include <hip/hip_runtime.h>
#include <hip/hip_bf16.h>
#include <math.h>

#define SEQ 8192
#define DIN 768
#define DOUT 64
#define QSCALE 0.1803368801111214f   // 0.125 * log2(e)

typedef __attribute__((ext_vector_type(8))) short short8;
typedef __attribute__((ext_vector_type(4))) short short4v;
typedef __attribute__((ext_vector_type(4))) float floatx4;
typedef __attribute__((ext_vector_type(2))) unsigned int uint2v;

// ---------------------------------------------------------------------------
// helpers
// ---------------------------------------------------------------------------
__device__ __forceinline__ void gload16(const void* g, void* l) {
    __builtin_amdgcn_global_load_lds(
        (const __attribute__((address_space(1))) unsigned int*)g,
        (__attribute__((address_space(3))) unsigned int*)l, 16, 0, 0);
}

__device__ __forceinline__ unsigned pack2(float a, float b) {
    __hip_bfloat162 h = __float22bfloat162_rn(make_float2(a, b));
    return *(unsigned*)&h;
}

__device__ __forceinline__ unsigned short bfbits(float f) {
    __hip_bfloat16 h = __float2bfloat16(f);
    return *(unsigned short*)&h;
}

__device__ __forceinline__ floatx4 mfma16(short4v a, short4v b, floatx4 c) {
#if __has_builtin(__builtin_amdgcn_mfma_f32_16x16x16bf16_1k)
    return __builtin_amdgcn_mfma_f32_16x16x16bf16_1k(a, b, c, 0, 0, 0);
#else
    asm("v_mfma_f32_16x16x16_bf16 %0, %1, %2, %0" : "+v"(c) : "v"(a), "v"(b));
    return c;
#endif
}

// ---------------------------------------------------------------------------
// Kernel 0: W (3 x [64][768] fp32) -> wbf [192][768] bf16 row-major
// ---------------------------------------------------------------------------
__global__ __launch_bounds__(256) void prep_w(
    const float* __restrict__ Wq, const float* __restrict__ Wk,
    const float* __restrict__ Wv, unsigned short* __restrict__ wbf)
{
    const int i = blockIdx.x * 256 + threadIdx.x;   // 0..18431
    const int base = i * 8;
    const int row = base / DIN;
    const int k = base % DIN;
    const float* src = (row < 64)  ? &Wq[(size_t)row * DIN + k]
                     : (row < 128) ? &Wk[(size_t)(row - 64) * DIN + k]
                                   : &Wv[(size_t)(row - 128) * DIN + k];
    const float4 f0 = *(const float4*)src;
    const float4 f1 = *(const float4*)(src + 4);
    uint4 v;
    v.x = pack2(f0.x, f0.y);
    v.y = pack2(f0.z, f0.w);
    v.z = pack2(f1.x, f1.y);
    v.w = pack2(f1.z, f1.w);
    *(uint4*)&wbf[base] = v;
}

// ---------------------------------------------------------------------------
// Kernel 1: QKV projection via MFMA.  grid 256 blocks x 256 thr (4 waves).
// Per block: 32 rows.  Wave (wid&1) = row half, (wid>>1) = nt half (6 tiles).
// Out: qbf [SEQ][64] bf16 (pre-scaled QSCALE), kbf [SEQ][64], vtbf [64][SEQ].
// LDS swizzle: byte(R,c) = R*128 + (((c>>3) ^ (R&7))<<4) + (c&7)*2
// ---------------------------------------------------------------------------
__global__ __launch_bounds__(256) void qkv_mfma(
    const float* __restrict__ x, const unsigned short* __restrict__ wbf,
    unsigned short* __restrict__ qbf, unsigned short* __restrict__ kbf,
    unsigned short* __restrict__ vtbf)
{
    __shared__ __align__(16) unsigned char xs[32 * 128];    // 4 KB
    __shared__ __align__(16) unsigned char wsm[192 * 128];  // 24 KB

    const int t = threadIdx.x;
    const int l = t & 63;
    const int wid = t >> 6;
    const int h = wid & 1;            // row half (16 rows)
    const int ntb = (wid >> 1) * 6;   // output-tile base (6 tiles of 16 cols)
    const int row0 = blockIdx.x * 32;

    floatx4 acc[6];
#pragma unroll
    for (int i = 0; i < 6; ++i) acc[i] = (floatx4){0.f, 0.f, 0.f, 0.f};

    for (int kc = 0; kc < 12; ++kc) {
        const int k0 = kc * 64;
        __syncthreads();

        // stage x tile (fp32 -> bf16, swizzled): thread -> (row R, slot)
        {
            const int R = t >> 3;          // 0..31
            const int sl = t & 7;          // 0..7
            const float4 a = *(const float4*)&x[(size_t)(row0 + R) * DIN + k0 + sl * 8];
            const float4 b = *(const float4*)&x[(size_t)(row0 + R) * DIN + k0 + sl * 8 + 4];
            uint4 v;
            v.x = pack2(a.x, a.y);
            v.y = pack2(a.z, a.w);
            v.z = pack2(b.x, b.y);
            v.w = pack2(b.z, b.w);
            *(uint4*)&xs[R * 128 + ((sl ^ (R & 7)) << 4)] = v;
        }
        // stage W tile via global_load_lds (pre-swizzled source)
        {
            const int Rr = l >> 3;
            const int sld = (l & 7) ^ Rr;
#pragma unroll
            for (int ss = 0; ss < 6; ++ss) {
                const int s = wid * 6 + ss;          // 0..23
                const int Rw = 8 * s + Rr;           // 0..191
                gload16(&wbf[(size_t)Rw * DIN + k0 + sld * 8], &wsm[s * 1024]);
            }
        }
        __syncthreads();

#pragma unroll
        for (int ks = 0; ks < 2; ++ks) {
            const int Rx = h * 16 + (l & 15);
            const int sl = (l >> 4) + 4 * ks;
            const short8 a = *(const short8*)&xs[Rx * 128 + ((sl ^ (Rx & 7)) << 4)];
#pragma unroll
            for (int j = 0; j < 6; ++j) {
                const int Rw = (ntb + j) * 16 + (l & 15);
                const short8 b = *(const short8*)&wsm[Rw * 128 + ((sl ^ (Rw & 7)) << 4)];
                acc[j] = __builtin_amdgcn_mfma_f32_16x16x32_bf16(a, b, acc[j], 0, 0, 0);
            }
        }
    }

    // epilogue: C layout row=(l>>4)*4+reg, col=l&15
    const int rb = row0 + h * 16 + ((l >> 4) << 2);
#pragma unroll
    for (int j = 0; j < 6; ++j) {
        const int nt = ntb + j;
#pragma unroll
        for (int r = 0; r < 4; ++r) {
            const float v = acc[j][r];
            const int R = rb + r;
            if (nt < 4) {
                qbf[(size_t)R * 64 + nt * 16 + (l & 15)] = bfbits(v * QSCALE);
            } else if (nt < 8) {
                kbf[(size_t)R * 64 + (nt - 4) * 16 + (l & 15)] = bfbits(v);
            } else {
                vtbf[(size_t)((nt - 8) * 16 + (l & 15)) * SEQ + R] = bfbits(v);
            }
        }
    }
}

// ---------------------------------------------------------------------------
// Kernel 2: flash attention via MFMA, swapped QK^T (S^T), in-register P.
// grid (SEQ/64, nsplit), 256 thr (4 waves x 16 q-rows).
// QK^T: mfma_16x16x32(A=K, B=Q^T) -> S^T; softmax lane-local per q-column;
// PV:   mfma_16x16x16(A=V^T, B=P^T) -> O^T, P never leaves registers.
// Epilogue transposes O^T -> O via LDS for coalesced stores.
// ---------------------------------------------------------------------------
__global__ __launch_bounds__(256, 4) void flash_mfma(
    const unsigned short* __restrict__ qbf,
    const unsigned short* __restrict__ kbf,
    const unsigned short* __restrict__ vtbf,
    float* __restrict__ opart,   // [nsplit][SEQ][64] (== out when direct)
    float* __restrict__ ml,      // [nsplit][SEQ][2]
    int nsplit, int direct)
{
    __shared__ __align__(16) unsigned char lds[40960];
    unsigned char* lq = lds;                 // 8 KB
    unsigned char* lkb = lds + 8192;         // 2 x 8 KB (dbuf K)
    unsigned char* lvb = lds + 24576;        // 2 x 8 KB (dbuf V^T)

    const int t = threadIdx.x;
    const int l = t & 63;
    const int g = l >> 4;        // 0..3
    const int q4 = l & 15;
    const int wid = t >> 6;
    const int row0 = blockIdx.x * 64;
    const int split = blockIdx.y;
    const int chunk = SEQ / nsplit;
    const int kbeg = split * chunk;
    const int NT = chunk / 64;

    // prologue: stage Q + K0 + V0
    {
        const int Rr = l >> 3;
        const int sl = (l & 7) ^ Rr;
#pragma unroll
        for (int ss = 0; ss < 2; ++ss) {
            const int s = wid * 2 + ss;
            const int R = 8 * s + Rr;
            gload16(&qbf[(size_t)(row0 + R) * 64 + sl * 8], lq + s * 1024);
            gload16(&kbf[(size_t)(kbeg + R) * 64 + sl * 8], lkb + s * 1024);
            gload16(&vtbf[(size_t)R * SEQ + kbeg + sl * 8], lvb + s * 1024);
        }
    }
    __syncthreads();

    // Q fragments (serve as MFMA B operand: B[k][col=q] == same registers)
    short8 qf[2];
#pragma unroll
    for (int ks = 0; ks < 2; ++ks) {
        const int R = wid * 16 + q4;
        const int sl = g + 4 * ks;
        qf[ks] = *(const short8*)&lq[R * 128 + ((sl ^ (R & 7)) << 4)];
    }

    floatx4 oacc[4];   // O^T[d = dt*16 + g*4 + r][q = wid*16 + q4]
#pragma unroll
    for (int i = 0; i < 4; ++i) oacc[i] = (floatx4){0.f, 0.f, 0.f, 0.f};
    float m_run = -INFINITY, l_run = 0.f;

    int cur = 0;
    for (int tt = 0; tt < NT; ++tt) {
        const unsigned char* lk = lkb + cur * 8192;
        const unsigned char* lv = lvb + cur * 8192;

        // prefetch next K/V tile
        if (tt + 1 < NT) {
            const int kt1 = kbeg + (tt + 1) * 64;
            const int Rr = l >> 3;
            const int sl = (l & 7) ^ Rr;
#pragma unroll
            for (int ss = 0; ss < 2; ++ss) {
                const int s = wid * 2 + ss;
                const int R = 8 * s + Rr;
                gload16(&kbf[(size_t)(kt1 + R) * 64 + sl * 8],
                        lkb + (cur ^ 1) * 8192 + s * 1024);
                gload16(&vtbf[(size_t)R * SEQ + kt1 + sl * 8],
                        lvb + (cur ^ 1) * 8192 + s * 1024);
            }
        }

        // ---- S^T = K Q^T : sacc[nt][r] = S[q][key = nt*16 + g*4 + r] ----
        floatx4 sacc[4];
#pragma unroll
        for (int i = 0; i < 4; ++i) sacc[i] = (floatx4){0.f, 0.f, 0.f, 0.f};
#pragma unroll
        for (int ks = 0; ks < 2; ++ks) {
            const int sl = g + 4 * ks;
#pragma unroll
            for (int nt = 0; nt < 4; ++nt) {
                const int R = nt * 16 + q4;
                const short8 kf = *(const short8*)&lk[R * 128 + ((sl ^ (R & 7)) << 4)];
                sacc[nt] = __builtin_amdgcn_mfma_f32_16x16x32_bf16(kf, qf[ks], sacc[nt], 0, 0, 0);
            }
        }

        // ---- online softmax (base-2), all lane-local + 2 shfl per reduce ----
        float mn = m_run;
#pragma unroll
        for (int nt = 0; nt < 4; ++nt)
#pragma unroll
            for (int r = 0; r < 4; ++r) mn = fmaxf(mn, sacc[nt][r]);
        mn = fmaxf(mn, __shfl_xor(mn, 16));
        mn = fmaxf(mn, __shfl_xor(mn, 32));

        const float alpha = exp2f(m_run - mn);
        m_run = mn;

        float p[4][4];
        float lt = 0.f;
#pragma unroll
        for (int nt = 0; nt < 4; ++nt)
#pragma unroll
            for (int r = 0; r < 4; ++r) {
                p[nt][r] = exp2f(sacc[nt][r] - mn);
                lt += p[nt][r];
            }
        lt += __shfl_xor(lt, 16);
        lt += __shfl_xor(lt, 32);
        l_run = l_run * alpha + lt;

#pragma unroll
        for (int dt = 0; dt < 4; ++dt) oacc[dt] *= alpha;

        // pack P^T fragments (in-register, feeds mfma16 B directly)
        unsigned pk[4][2];
#pragma unroll
        for (int nt = 0; nt < 4; ++nt) {
            pk[nt][0] = pack2(p[nt][0], p[nt][1]);
            pk[nt][1] = pack2(p[nt][2], p[nt][3]);
        }

        // ---- O^T += V^T P^T ----
#pragma unroll
        for (int kb = 0; kb < 4; ++kb) {
            const short4v bfr = __builtin_bit_cast(short4v, (uint2v){pk[kb][0], pk[kb][1]});
            const int sl = (kb * 2 + (g >> 1));
#pragma unroll
            for (int dt = 0; dt < 4; ++dt) {
                const int R = dt * 16 + q4;
                const short4v a = *(const short4v*)&lv[R * 128 +
                    (((sl ^ (R & 7))) << 4) + ((g & 1) << 3)];
                oacc[dt] = mfma16(a, bfr, oacc[dt]);
            }
        }

        __syncthreads();   // dbuf swap: prefetch landed, all waves done with cur
        cur ^= 1;
    }

    // ---- epilogue: O^T -> O via LDS transpose, coalesced stores ----
    float* trans = (float*)(lds + 8192);   // [64][68] fp32 = 17408 B (kv region free)
    {
        const int qrow = wid * 16 + q4;
        const float sc = direct ? (1.0f / l_run) : 1.0f;
#pragma unroll
        for (int dt = 0; dt < 4; ++dt) {
            floatx4 v = oacc[dt] * sc;
            *(floatx4*)&trans[qrow * 68 + dt * 16 + g * 4] = v;
        }
        if (!direct && l < 16) {
            const size_t mrow = (size_t)split * SEQ + row0 + wid * 16 + l;
            ml[mrow * 2 + 0] = m_run;
            ml[mrow * 2 + 1] = l_run;
        }
    }
    __syncthreads();

    float* outbase = direct ? opart : opart + (size_t)split * SEQ * 64;
#pragma unroll
    for (int it = 0; it < 4; ++it) {
        const int row = it * 16 + (t >> 4);
        const floatx4 v = *(const floatx4*)&trans[row * 68 + (t & 15) * 4];
        *(floatx4*)&outbase[(size_t)(row0 + row) * 64 + (t & 15) * 4] = v;
    }
}

// ---------------------------------------------------------------------------
// Kernel 3: combine split partials (log-sum-exp merge, base-2)
// ---------------------------------------------------------------------------
__global__ __launch_bounds__(256) void combine_kernel(
    const float* __restrict__ opart, const float* __restrict__ ml,
    float* __restrict__ out, int nsplit)
{
    const int idx = blockIdx.x * 256 + threadIdx.x;
    if (idx >= SEQ * DOUT) return;
    const int row = idx >> 6;

    float M = -INFINITY;
    for (int s = 0; s < nsplit; ++s)
        M = fmaxf(M, ml[((size_t)s * SEQ + row) * 2]);

    float denom = 0.f, acc = 0.f;
    for (int s = 0; s < nsplit; ++s) {
        const float w = exp2f(ml[((size_t)s * SEQ + row) * 2] - M);
        denom += ml[((size_t)s * SEQ + row) * 2 + 1] * w;
        acc += opart[(size_t)s * SEQ * DOUT + idx] * w;
    }
    out[idx] = acc / denom;
}

// ---------------------------------------------------------------------------
extern "C" void kernel_launch(void* const* d_in, const int* in_sizes, int n_in,
                              void* d_out, int out_size, void* d_ws, size_t ws_size,
                              hipStream_t stream)
{
    const float* x  = (const float*)d_in[0];
    const float* Wq = (const float*)d_in[1];
    const float* Wk = (const float*)d_in[2];
    const float* Wv = (const float*)d_in[3];
    float* out = (float*)d_out;
    unsigned char* ws = (unsigned char*)d_ws;

    const size_t wbf_b = (size_t)192 * DIN * 2;
    const size_t qkv_b = (size_t)SEQ * 64 * 2;
    size_t off = 0;
    unsigned short* wbf  = (unsigned short*)(ws + off); off += wbf_b;
    unsigned short* qbf  = (unsigned short*)(ws + off); off += qkv_b;
    unsigned short* kbf  = (unsigned short*)(ws + off); off += qkv_b;
    unsigned short* vtbf = (unsigned short*)(ws + off); off += qkv_b;

    const size_t per_split = (size_t)SEQ * 64 * 4 + (size_t)SEQ * 2 * 4;
    int nsplit = 0;
    if      (ws_size >= off + 8 * per_split) nsplit = 8;
    else if (ws_size >= off + 4 * per_split) nsplit = 4;
    else if (ws_size >= off + 2 * per_split) nsplit = 2;

    prep_w<<<72, 256, 0, stream>>>(Wq, Wk, Wv, wbf);
    qkv_mfma<<<SEQ / 32, 256, 0, stream>>>(x, wbf, qbf, kbf, vtbf);

    if (nsplit == 0) {
        flash_mfma<<<dim3(SEQ / 64, 1), 256, 0, stream>>>(
            qbf, kbf, vtbf, out, nullptr, 1, 1);
    } else {
        float* opart = (float*)(ws + off);
        float* mlp   = (float*)(ws + off + (size_t)nsplit * SEQ * 64 * 4);
        flash_mfma<<<dim3(SEQ / 64, nsplit), 256, 0, stream>>>(
            qbf, kbf, vtbf, opart, mlp, nsplit, 0);
        combine_kernel<<<(SEQ * DOUT + 255) / 256, 256, 0, stream>>>(opart, mlp, out, nsplit);
    }
}

// Round 4
// 69.253 us; speedup vs baseline: 4.7737x; 1.1419x over previous
//
#include <hip/hip_runtime.h>
#include <hip/hip_bf16.h>
#include <math.h>

#define SEQ 8192
#define DIN 768
#define DOUT 64
#define QSCALE 0.1803368801111214f   // 0.125 * log2(e)

typedef __attribute__((ext_vector_type(8))) short short8;
typedef __attribute__((ext_vector_type(4))) short short4v;
typedef __attribute__((ext_vector_type(4))) float floatx4;
typedef __attribute__((ext_vector_type(2))) unsigned int uint2v;

// ---------------------------------------------------------------------------
// helpers
// ---------------------------------------------------------------------------
__device__ __forceinline__ void gload16(const void* g, void* l) {
    __builtin_amdgcn_global_load_lds(
        (const __attribute__((address_space(1))) unsigned int*)g,
        (__attribute__((address_space(3))) unsigned int*)l, 16, 0, 0);
}

__device__ __forceinline__ unsigned pack2(float a, float b) {
    __hip_bfloat162 h = __float22bfloat162_rn(make_float2(a, b));
    return *(unsigned*)&h;
}

__device__ __forceinline__ unsigned short bfbits(float f) {
    __hip_bfloat16 h = __float2bfloat16(f);
    return *(unsigned short*)&h;
}

__device__ __forceinline__ float exp2r(float x) {
#if __has_builtin(__builtin_amdgcn_exp2f)
    return __builtin_amdgcn_exp2f(x);
#else
    float r; asm("v_exp_f32 %0, %1" : "=v"(r) : "v"(x)); return r;
#endif
}

__device__ __forceinline__ floatx4 max4(floatx4 a, floatx4 b) {
    floatx4 r;
    r[0] = fmaxf(a[0], b[0]); r[1] = fmaxf(a[1], b[1]);
    r[2] = fmaxf(a[2], b[2]); r[3] = fmaxf(a[3], b[3]);
    return r;
}

__device__ __forceinline__ floatx4 mfma16(short4v a, short4v b, floatx4 c) {
#if __has_builtin(__builtin_amdgcn_mfma_f32_16x16x16bf16_1k)
    return __builtin_amdgcn_mfma_f32_16x16x16bf16_1k(a, b, c, 0, 0, 0);
#else
    asm("v_mfma_f32_16x16x16_bf16 %0, %1, %2, %0" : "+v"(c) : "v"(a), "v"(b));
    return c;
#endif
}

// ---------------------------------------------------------------------------
// Kernel 0: W (3 x [64][768] fp32) -> wbf [192][768] bf16 row-major
// ---------------------------------------------------------------------------
__global__ __launch_bounds__(256) void prep_w(
    const float* __restrict__ Wq, const float* __restrict__ Wk,
    const float* __restrict__ Wv, unsigned short* __restrict__ wbf)
{
    const int i = blockIdx.x * 256 + threadIdx.x;
    const int base = i * 8;
    const int row = base / DIN;
    const int k = base % DIN;
    const float* src = (row < 64)  ? &Wq[(size_t)row * DIN + k]
                     : (row < 128) ? &Wk[(size_t)(row - 64) * DIN + k]
                                   : &Wv[(size_t)(row - 128) * DIN + k];
    const float4 f0 = *(const float4*)src;
    const float4 f1 = *(const float4*)(src + 4);
    uint4 v;
    v.x = pack2(f0.x, f0.y);
    v.y = pack2(f0.z, f0.w);
    v.z = pack2(f1.x, f1.y);
    v.w = pack2(f1.z, f1.w);
    *(uint4*)&wbf[base] = v;
}

// ---------------------------------------------------------------------------
// Kernel 1: QKV projection via MFMA, double-buffered staging.
// grid 256 x 256 thr (4 waves).  Per block 32 rows.
// Out: qbf [SEQ][64] (pre-scaled QSCALE), kbf [SEQ][64], vtbf [64][SEQ].
// LDS swizzle: byte(R,c) = R*128 + (((c>>3) ^ (R&7))<<4) + (c&7)*2
// ---------------------------------------------------------------------------
__global__ __launch_bounds__(256) void qkv_mfma(
    const float* __restrict__ x, const unsigned short* __restrict__ wbf,
    unsigned short* __restrict__ qbf, unsigned short* __restrict__ kbf,
    unsigned short* __restrict__ vtbf)
{
    __shared__ __align__(16) unsigned char xs[2][32 * 128];    // 2 x 4 KB
    __shared__ __align__(16) unsigned char wsm[2][192 * 128];  // 2 x 24 KB

    const int t = threadIdx.x;
    const int l = t & 63;
    const int wid = t >> 6;
    const int h = wid & 1;
    const int ntb = (wid >> 1) * 6;
    const int row0 = blockIdx.x * 32;

    const int Rx_st = t >> 3;          // x-stage row 0..31
    const int slx   = t & 7;           // x-stage slot
    const int Rr    = l >> 3;          // W-stage sub-row
    const int sld   = (l & 7) ^ Rr;    // W-stage pre-swizzled slot

    floatx4 acc[6];
#pragma unroll
    for (int i = 0; i < 6; ++i) acc[i] = (floatx4){0.f, 0.f, 0.f, 0.f};

    // ---- prologue: stage chunk 0 ----
    {
        const float4 a = *(const float4*)&x[(size_t)(row0 + Rx_st) * DIN + slx * 8];
        const float4 b = *(const float4*)&x[(size_t)(row0 + Rx_st) * DIN + slx * 8 + 4];
        uint4 v;
        v.x = pack2(a.x, a.y); v.y = pack2(a.z, a.w);
        v.z = pack2(b.x, b.y); v.w = pack2(b.z, b.w);
        *(uint4*)&xs[0][Rx_st * 128 + ((slx ^ (Rx_st & 7)) << 4)] = v;
#pragma unroll
        for (int ss = 0; ss < 6; ++ss) {
            const int s = wid * 6 + ss;
            const int Rw = 8 * s + Rr;
            gload16(&wbf[(size_t)Rw * DIN + sld * 8], &wsm[0][s * 1024]);
        }
    }

    int cur = 0;
    for (int kc = 0; kc < 12; ++kc) {
        __syncthreads();   // buf[cur] fully staged

        float4 xa, xb;
        const bool more = (kc + 1 < 12);
        if (more) {
            const int k1 = (kc + 1) * 64;
            // issue next W gload + next x global loads (overlap with compute)
#pragma unroll
            for (int ss = 0; ss < 6; ++ss) {
                const int s = wid * 6 + ss;
                const int Rw = 8 * s + Rr;
                gload16(&wbf[(size_t)Rw * DIN + k1 + sld * 8], &wsm[cur ^ 1][s * 1024]);
            }
            xa = *(const float4*)&x[(size_t)(row0 + Rx_st) * DIN + k1 + slx * 8];
            xb = *(const float4*)&x[(size_t)(row0 + Rx_st) * DIN + k1 + slx * 8 + 4];
        }

        // ---- compute on buf[cur] ----
#pragma unroll
        for (int ks = 0; ks < 2; ++ks) {
            const int Rxx = h * 16 + (l & 15);
            const int sl = (l >> 4) + 4 * ks;
            const short8 a = *(const short8*)&xs[cur][Rxx * 128 + ((sl ^ (Rxx & 7)) << 4)];
#pragma unroll
            for (int j = 0; j < 6; ++j) {
                const int Rw = (ntb + j) * 16 + (l & 15);
                const short8 b = *(const short8*)&wsm[cur][Rw * 128 + ((sl ^ (Rw & 7)) << 4)];
                acc[j] = __builtin_amdgcn_mfma_f32_16x16x32_bf16(a, b, acc[j], 0, 0, 0);
            }
        }

        if (more) {
            uint4 v;
            v.x = pack2(xa.x, xa.y); v.y = pack2(xa.z, xa.w);
            v.z = pack2(xb.x, xb.y); v.w = pack2(xb.z, xb.w);
            *(uint4*)&xs[cur ^ 1][Rx_st * 128 + ((slx ^ (Rx_st & 7)) << 4)] = v;
        }
        cur ^= 1;
    }

    // epilogue: C layout row=(l>>4)*4+reg, col=l&15
    const int rb = row0 + h * 16 + ((l >> 4) << 2);
#pragma unroll
    for (int j = 0; j < 6; ++j) {
        const int nt = ntb + j;
#pragma unroll
        for (int r = 0; r < 4; ++r) {
            const float v = acc[j][r];
            const int R = rb + r;
            if (nt < 4) {
                qbf[(size_t)R * 64 + nt * 16 + (l & 15)] = bfbits(v * QSCALE);
            } else if (nt < 8) {
                kbf[(size_t)R * 64 + (nt - 4) * 16 + (l & 15)] = bfbits(v);
            } else {
                vtbf[(size_t)((nt - 8) * 16 + (l & 15)) * SEQ + R] = bfbits(v);
            }
        }
    }
}

// ---------------------------------------------------------------------------
// Kernel 2: flash attention, swapped QK^T, in-register P, defer-max softmax.
// grid (SEQ/64, nsplit), 256 thr (4 waves x 16 q-rows).
// ---------------------------------------------------------------------------
__global__ __launch_bounds__(256, 4) void flash_mfma(
    const unsigned short* __restrict__ qbf,
    const unsigned short* __restrict__ kbf,
    const unsigned short* __restrict__ vtbf,
    float* __restrict__ opart,   // [nsplit][SEQ][64] (== out when direct)
    float* __restrict__ ml,      // [nsplit][SEQ][2]
    int nsplit, int direct)
{
    __shared__ __align__(16) unsigned char lds[32768];
    unsigned char* lkb = lds;              // 2 x 8 KB (dbuf K)
    unsigned char* lvb = lds + 16384;      // 2 x 8 KB (dbuf V^T)

    const int t = threadIdx.x;
    const int l = t & 63;
    const int g = l >> 4;
    const int q4 = l & 15;
    const int wid = t >> 6;
    const int row0 = blockIdx.x * 64;
    const int split = blockIdx.y;
    const int chunk = SEQ / nsplit;
    const int kbeg = split * chunk;
    const int NT = chunk / 64;

    // Q fragments straight from global (L2-hot, once per block)
    short8 qf[2];
#pragma unroll
    for (int ks = 0; ks < 2; ++ks)
        qf[ks] = *(const short8*)&qbf[(size_t)(row0 + wid * 16 + q4) * 64 + (g + 4 * ks) * 8];

    // prologue: stage K0 + V0
    {
        const int Rr = l >> 3;
        const int sl = (l & 7) ^ Rr;
#pragma unroll
        for (int ss = 0; ss < 2; ++ss) {
            const int s = wid * 2 + ss;
            const int R = 8 * s + Rr;
            gload16(&kbf[(size_t)(kbeg + R) * 64 + sl * 8], lkb + s * 1024);
            gload16(&vtbf[(size_t)R * SEQ + kbeg + sl * 8], lvb + s * 1024);
        }
    }
    __syncthreads();

    floatx4 oacc[4];   // O^T[d = dt*16 + g*4 + r][q = wid*16 + q4]
#pragma unroll
    for (int i = 0; i < 4; ++i) oacc[i] = (floatx4){0.f, 0.f, 0.f, 0.f};
    float m_run = -INFINITY, l_run = 0.f;

    int cur = 0;
    for (int tt = 0; tt < NT; ++tt) {
        const unsigned char* lk = lkb + cur * 8192;
        const unsigned char* lv = lvb + cur * 8192;

        // prefetch next K/V tile
        if (tt + 1 < NT) {
            const int kt1 = kbeg + (tt + 1) * 64;
            const int Rr = l >> 3;
            const int sl = (l & 7) ^ Rr;
#pragma unroll
            for (int ss = 0; ss < 2; ++ss) {
                const int s = wid * 2 + ss;
                const int R = 8 * s + Rr;
                gload16(&kbf[(size_t)(kt1 + R) * 64 + sl * 8],
                        lkb + (cur ^ 1) * 8192 + s * 1024);
                gload16(&vtbf[(size_t)R * SEQ + kt1 + sl * 8],
                        lvb + (cur ^ 1) * 8192 + s * 1024);
            }
        }

        // ---- S^T = K Q^T : sacc[nt][r] = S[q][key = nt*16 + g*4 + r] ----
        floatx4 sacc[4];
#pragma unroll
        for (int i = 0; i < 4; ++i) sacc[i] = (floatx4){0.f, 0.f, 0.f, 0.f};
#pragma unroll
        for (int ks = 0; ks < 2; ++ks) {
            const int sl = g + 4 * ks;
#pragma unroll
            for (int nt = 0; nt < 4; ++nt) {
                const int R = nt * 16 + q4;
                const short8 kf = *(const short8*)&lk[R * 128 + ((sl ^ (R & 7)) << 4)];
                sacc[nt] = __builtin_amdgcn_mfma_f32_16x16x32_bf16(kf, qf[ks], sacc[nt], 0, 0, 0);
            }
        }

        // ---- tile max (packed) ----
        const floatx4 mm = max4(max4(sacc[0], sacc[1]), max4(sacc[2], sacc[3]));
        float pm = fmaxf(fmaxf(mm[0], mm[1]), fmaxf(mm[2], mm[3]));
        pm = fmaxf(pm, __shfl_xor(pm, 16));
        pm = fmaxf(pm, __shfl_xor(pm, 32));

        // ---- defer-max: rescale only when tile max outgrows running max ----
        if (__any(pm > m_run + 8.0f)) {
            const float mn = fmaxf(m_run, pm);
            const float alpha = exp2r(m_run - mn);
            m_run = mn;
            l_run *= alpha;
#pragma unroll
            for (int dt = 0; dt < 4; ++dt) oacc[dt] *= alpha;
        }

        // ---- p = 2^(s - m_run), packed sub + raw exp ----
        floatx4 pv4[4];
#pragma unroll
        for (int nt = 0; nt < 4; ++nt) {
            floatx4 d = sacc[nt];
            d[0] -= m_run; d[1] -= m_run; d[2] -= m_run; d[3] -= m_run;
            pv4[nt][0] = exp2r(d[0]); pv4[nt][1] = exp2r(d[1]);
            pv4[nt][2] = exp2r(d[2]); pv4[nt][3] = exp2r(d[3]);
        }
        const floatx4 psum = (pv4[0] + pv4[1]) + (pv4[2] + pv4[3]);
        float lt = (psum[0] + psum[1]) + (psum[2] + psum[3]);
        lt += __shfl_xor(lt, 16);
        lt += __shfl_xor(lt, 32);
        l_run += lt;

        // ---- O^T += V^T P^T (P in-register) ----
#pragma unroll
        for (int kb = 0; kb < 4; ++kb) {
            const unsigned p0 = pack2(pv4[kb][0], pv4[kb][1]);
            const unsigned p1 = pack2(pv4[kb][2], pv4[kb][3]);
            const short4v bfr = __builtin_bit_cast(short4v, (uint2v){p0, p1});
            const int sl = kb * 2 + (g >> 1);
#pragma unroll
            for (int dt = 0; dt < 4; ++dt) {
                const int R = dt * 16 + q4;
                const short4v a = *(const short4v*)&lv[R * 128 +
                    ((sl ^ (R & 7)) << 4) + ((g & 1) << 3)];
                oacc[dt] = mfma16(a, bfr, oacc[dt]);
            }
        }

        __syncthreads();   // dbuf swap
        cur ^= 1;
    }

    // ---- epilogue: O^T -> O via LDS transpose, coalesced stores ----
    float* trans = (float*)lds;   // [64][68] fp32 = 17408 B (kv buffers done)
    {
        const int qrow = wid * 16 + q4;
        const float sc = direct ? (1.0f / l_run) : 1.0f;
#pragma unroll
        for (int dt = 0; dt < 4; ++dt) {
            floatx4 v = oacc[dt] * sc;
            *(floatx4*)&trans[qrow * 68 + dt * 16 + g * 4] = v;
        }
        if (!direct && l < 16) {
            const size_t mrow = (size_t)split * SEQ + row0 + wid * 16 + l;
            ml[mrow * 2 + 0] = m_run;
            ml[mrow * 2 + 1] = l_run;
        }
    }
    __syncthreads();

    float* outbase = direct ? opart : opart + (size_t)split * SEQ * 64;
#pragma unroll
    for (int it = 0; it < 4; ++it) {
        const int row = it * 16 + (t >> 4);
        const floatx4 v = *(const floatx4*)&trans[row * 68 + (t & 15) * 4];
        *(floatx4*)&outbase[(size_t)(row0 + row) * 64 + (t & 15) * 4] = v;
    }
}

// ---------------------------------------------------------------------------
// Kernel 3: combine split partials (log-sum-exp merge, base-2)
// ---------------------------------------------------------------------------
__global__ __launch_bounds__(256) void combine_kernel(
    const float* __restrict__ opart, const float* __restrict__ ml,
    float* __restrict__ out, int nsplit)
{
    const int idx = blockIdx.x * 256 + threadIdx.x;
    if (idx >= SEQ * DOUT) return;
    const int row = idx >> 6;

    float M = -INFINITY;
    for (int s = 0; s < nsplit; ++s)
        M = fmaxf(M, ml[((size_t)s * SEQ + row) * 2]);

    float denom = 0.f, acc = 0.f;
    for (int s = 0; s < nsplit; ++s) {
        const float w = exp2r(ml[((size_t)s * SEQ + row) * 2] - M);
        denom += ml[((size_t)s * SEQ + row) * 2 + 1] * w;
        acc += opart[(size_t)s * SEQ * DOUT + idx] * w;
    }
    out[idx] = acc / denom;
}

// ---------------------------------------------------------------------------
extern "C" void kernel_launch(void* const* d_in, const int* in_sizes, int n_in,
                              void* d_out, int out_size, void* d_ws, size_t ws_size,
                              hipStream_t stream)
{
    const float* x  = (const float*)d_in[0];
    const float* Wq = (const float*)d_in[1];
    const float* Wk = (const float*)d_in[2];
    const float* Wv = (const float*)d_in[3];
    float* out = (float*)d_out;
    unsigned char* ws = (unsigned char*)d_ws;

    const size_t wbf_b = (size_t)192 * DIN * 2;
    const size_t qkv_b = (size_t)SEQ * 64 * 2;
    size_t off = 0;
    unsigned short* wbf  = (unsigned short*)(ws + off); off += wbf_b;
    unsigned short* qbf  = (unsigned short*)(ws + off); off += qkv_b;
    unsigned short* kbf  = (unsigned short*)(ws + off); off += qkv_b;
    unsigned short* vtbf = (unsigned short*)(ws + off); off += qkv_b;

    const size_t per_split = (size_t)SEQ * 64 * 4 + (size_t)SEQ * 2 * 4;
    int nsplit = 0;
    if      (ws_size >= off + 8 * per_split) nsplit = 8;
    else if (ws_size >= off + 4 * per_split) nsplit = 4;
    else if (ws_size >= off + 2 * per_split) nsplit = 2;

    prep_w<<<72, 256, 0, stream>>>(Wq, Wk, Wv, wbf);
    qkv_mfma<<<SEQ / 32, 256, 0, stream>>>(x, wbf, qbf, kbf, vtbf);

    if (nsplit == 0) {
        flash_mfma<<<dim3(SEQ / 64, 1), 256, 0, stream>>>(
            qbf, kbf, vtbf, out, nullptr, 1, 1);
    } else {
        float* opart = (float*)(ws + off);
        float* mlp   = (float*)(ws + off + (size_t)nsplit * SEQ * 64 * 4);
        flash_mfma<<<dim3(SEQ / 64, nsplit), 256, 0, stream>>>(
            qbf, kbf, vtbf, opart, mlp, nsplit, 0);
        combine_kernel<<<(SEQ * DOUT + 255) / 256, 256, 0, stream>>>(opart, mlp, out, nsplit);
    }
}

// Round 5
// 61.222 us; speedup vs baseline: 5.3999x; 1.1312x over previous
//
#include <hip/hip_runtime.h>
#include <hip/hip_bf16.h>
#include <math.h>

#define SEQ 8192
#define DIN 768
#define DOUT 64
#define QSCALE 0.1803368801111214f   // 0.125 * log2(e)

typedef __attribute__((ext_vector_type(8))) short short8;
typedef __attribute__((ext_vector_type(4))) short short4v;
typedef __attribute__((ext_vector_type(4))) float floatx4;
typedef __attribute__((ext_vector_type(2))) unsigned int uint2v;

// ---------------------------------------------------------------------------
// helpers
// ---------------------------------------------------------------------------
__device__ __forceinline__ void gload16(const void* g, void* l) {
    __builtin_amdgcn_global_load_lds(
        (const __attribute__((address_space(1))) unsigned int*)g,
        (__attribute__((address_space(3))) unsigned int*)l, 16, 0, 0);
}

__device__ __forceinline__ unsigned pack2(float a, float b) {
    __hip_bfloat162 h = __float22bfloat162_rn(make_float2(a, b));
    return *(unsigned*)&h;
}

__device__ __forceinline__ unsigned short bfbits(float f) {
    __hip_bfloat16 h = __float2bfloat16(f);
    return *(unsigned short*)&h;
}

__device__ __forceinline__ float exp2r(float x) {
#if __has_builtin(__builtin_amdgcn_exp2f)
    return __builtin_amdgcn_exp2f(x);
#else
    float r; asm("v_exp_f32 %0, %1" : "=v"(r) : "v"(x)); return r;
#endif
}

__device__ __forceinline__ floatx4 max4(floatx4 a, floatx4 b) {
    floatx4 r;
    r[0] = fmaxf(a[0], b[0]); r[1] = fmaxf(a[1], b[1]);
    r[2] = fmaxf(a[2], b[2]); r[3] = fmaxf(a[3], b[3]);
    return r;
}

__device__ __forceinline__ floatx4 mfma16(short4v a, short4v b, floatx4 c) {
#if __has_builtin(__builtin_amdgcn_mfma_f32_16x16x16bf16_1k)
    return __builtin_amdgcn_mfma_f32_16x16x16bf16_1k(a, b, c, 0, 0, 0);
#else
    asm("v_mfma_f32_16x16x16_bf16 %0, %1, %2, %0" : "+v"(c) : "v"(a), "v"(b));
    return c;
#endif
}

// swizzled 16B-slot position within a 256 B row (16 slots)
__device__ __forceinline__ int phs(int s, int R) {
    return (s & 8) | ((s ^ R) & 7);
}

// ---------------------------------------------------------------------------
// Kernel 0: W (3 x [64][768] fp32) -> wbf [192][768] bf16 row-major
// ---------------------------------------------------------------------------
__global__ __launch_bounds__(256) void prep_w(
    const float* __restrict__ Wq, const float* __restrict__ Wk,
    const float* __restrict__ Wv, unsigned short* __restrict__ wbf)
{
    const int i = blockIdx.x * 256 + threadIdx.x;
    const int base = i * 8;
    const int row = base / DIN;
    const int k = base % DIN;
    const float* src = (row < 64)  ? &Wq[(size_t)row * DIN + k]
                     : (row < 128) ? &Wk[(size_t)(row - 64) * DIN + k]
                                   : &Wv[(size_t)(row - 128) * DIN + k];
    const float4 f0 = *(const float4*)src;
    const float4 f1 = *(const float4*)(src + 4);
    uint4 v;
    v.x = pack2(f0.x, f0.y);
    v.y = pack2(f0.z, f0.w);
    v.z = pack2(f1.x, f1.y);
    v.w = pack2(f1.z, f1.w);
    *(uint4*)&wbf[base] = v;
}

// ---------------------------------------------------------------------------
// Kernel 1: QKV projection via MFMA, BK=128, double-buffered staging.
// grid 256 x 256 thr (4 waves).  Per block 32 rows, 6 K-chunks.
// Out: qbf [SEQ][64] (pre-scaled QSCALE), kbf [SEQ][64], vtbf [64][SEQ].
// Rows are 256 B (128 bf16); 16B slots swizzled via phs().
// ---------------------------------------------------------------------------
__global__ __launch_bounds__(256) void qkv_mfma(
    const float* __restrict__ x, const unsigned short* __restrict__ wbf,
    unsigned short* __restrict__ qbf, unsigned short* __restrict__ kbf,
    unsigned short* __restrict__ vtbf)
{
    __shared__ __align__(16) unsigned char xs[2][32 * 256];    // 2 x 8 KB
    __shared__ __align__(16) unsigned char wsm[2][192 * 256];  // 2 x 48 KB

    const int t = threadIdx.x;
    const int l = t & 63;
    const int wid = t >> 6;
    const int h = wid & 1;
    const int ntb = (wid >> 1) * 6;
    const int q4_ = l & 15;
    const int row0 = blockIdx.x * 32;

    const int Rx_st = t >> 3;          // x-stage row 0..31
    const int s0    = (t & 7) * 2;     // x-stage slots s0, s0+1
    const int Rr4   = l >> 4;          // W-stage sub-row 0..3
    const int s16   = l & 15;
    // inverse-swizzle source slot for W gload (dest phys slot == s16)
    //   (per-strip row parity handled below since Rw depends on strip)

    floatx4 acc[6];
#pragma unroll
    for (int i = 0; i < 6; ++i) acc[i] = (floatx4){0.f, 0.f, 0.f, 0.f};

    // ---- stage helpers (macros avoid lambdas) ----
#define STAGE_X(buf, k0)                                                      \
    {                                                                         \
        _Pragma("unroll")                                                     \
        for (int ss = 0; ss < 2; ++ss) {                                      \
            const int sl = s0 + ss;                                           \
            const float4 a = *(const float4*)&x[(size_t)(row0 + Rx_st) * DIN + (k0) + sl * 8]; \
            const float4 b = *(const float4*)&x[(size_t)(row0 + Rx_st) * DIN + (k0) + sl * 8 + 4]; \
            uint4 v;                                                          \
            v.x = pack2(a.x, a.y); v.y = pack2(a.z, a.w);                     \
            v.z = pack2(b.x, b.y); v.w = pack2(b.z, b.w);                     \
            *(uint4*)&xs[buf][Rx_st * 256 + phs(sl, Rx_st) * 16] = v;         \
        }                                                                     \
    }

#define STAGE_W(buf, k0)                                                      \
    {                                                                         \
        _Pragma("unroll")                                                     \
        for (int ss = 0; ss < 12; ++ss) {                                     \
            const int s = wid * 12 + ss;           /* 0..47 */                \
            const int Rw = 4 * s + Rr4;            /* 0..191 */               \
            const int slog = (s16 & 8) | ((s16 ^ Rw) & 7);                    \
            gload16(&wbf[(size_t)Rw * DIN + (k0) + slog * 8], &wsm[buf][s * 1024]); \
        }                                                                     \
    }

    // ---- prologue: stage chunk 0 ----
    STAGE_X(0, 0)
    STAGE_W(0, 0)

    int cur = 0;
    for (int kc = 0; kc < 6; ++kc) {
        __syncthreads();   // buf[cur] fully staged

        float4 xa[2], xb[2];
        const bool more = (kc + 1 < 6);
        if (more) {
            const int k1 = (kc + 1) * 128;
            STAGE_W(cur ^ 1, k1)
#pragma unroll
            for (int ss = 0; ss < 2; ++ss) {
                const int sl = s0 + ss;
                xa[ss] = *(const float4*)&x[(size_t)(row0 + Rx_st) * DIN + k1 + sl * 8];
                xb[ss] = *(const float4*)&x[(size_t)(row0 + Rx_st) * DIN + k1 + sl * 8 + 4];
            }
        }

        // ---- compute on buf[cur]: 4 k-steps x 6 output tiles ----
#pragma unroll
        for (int ks = 0; ks < 4; ++ks) {
            const int g = l >> 4;
            const int slot = g + 4 * ks;
            const int Rxx = h * 16 + q4_;
            const short8 a = *(const short8*)&xs[cur][Rxx * 256 + phs(slot, Rxx) * 16];
#pragma unroll
            for (int j = 0; j < 6; ++j) {
                const int Rw = (ntb + j) * 16 + q4_;
                const short8 b = *(const short8*)&wsm[cur][Rw * 256 + phs(slot, Rw) * 16];
                acc[j] = __builtin_amdgcn_mfma_f32_16x16x32_bf16(a, b, acc[j], 0, 0, 0);
            }
        }

        if (more) {
#pragma unroll
            for (int ss = 0; ss < 2; ++ss) {
                const int sl = s0 + ss;
                uint4 v;
                v.x = pack2(xa[ss].x, xa[ss].y); v.y = pack2(xa[ss].z, xa[ss].w);
                v.z = pack2(xb[ss].x, xb[ss].y); v.w = pack2(xb[ss].z, xb[ss].w);
                *(uint4*)&xs[cur ^ 1][Rx_st * 256 + phs(sl, Rx_st) * 16] = v;
            }
        }
        cur ^= 1;
    }

    // epilogue: C layout row=(l>>4)*4+reg, col=l&15
    const int rb = row0 + h * 16 + ((l >> 4) << 2);
#pragma unroll
    for (int j = 0; j < 6; ++j) {
        const int nt = ntb + j;
#pragma unroll
        for (int r = 0; r < 4; ++r) {
            const float v = acc[j][r];
            const int R = rb + r;
            if (nt < 4) {
                qbf[(size_t)R * 64 + nt * 16 + q4_] = bfbits(v * QSCALE);
            } else if (nt < 8) {
                kbf[(size_t)R * 64 + (nt - 4) * 16 + q4_] = bfbits(v);
            } else {
                vtbf[(size_t)((nt - 8) * 16 + q4_) * SEQ + R] = bfbits(v);
            }
        }
    }
#undef STAGE_X
#undef STAGE_W
}

// ---------------------------------------------------------------------------
// Kernel 2: flash attention, swapped QK^T, in-register P, defer-max softmax,
// no per-tile cross-lane ops (ballot-gated rescale, deferred l-sum).
// grid (SEQ/64, nsplit), 256 thr (4 waves x 16 q-rows).
// ---------------------------------------------------------------------------
__global__ __launch_bounds__(256, 4) void flash_mfma(
    const unsigned short* __restrict__ qbf,
    const unsigned short* __restrict__ kbf,
    const unsigned short* __restrict__ vtbf,
    float* __restrict__ opart,   // [nsplit][SEQ][64] (== out when direct)
    float* __restrict__ ml,      // [nsplit][SEQ][2]
    int nsplit, int direct)
{
    __shared__ __align__(16) unsigned char lds[32768];
    unsigned char* lkb = lds;              // 2 x 8 KB (dbuf K)
    unsigned char* lvb = lds + 16384;      // 2 x 8 KB (dbuf V^T)

    const int t = threadIdx.x;
    const int l = t & 63;
    const int g = l >> 4;
    const int q4 = l & 15;
    const int wid = t >> 6;
    const int row0 = blockIdx.x * 64;
    const int split = blockIdx.y;
    const int chunk = SEQ / nsplit;
    const int kbeg = split * chunk;
    const int NT = chunk / 64;

    // Q fragments straight from global (L2-hot, once per block)
    short8 qf[2];
#pragma unroll
    for (int ks = 0; ks < 2; ++ks)
        qf[ks] = *(const short8*)&qbf[(size_t)(row0 + wid * 16 + q4) * 64 + (g + 4 * ks) * 8];

    // prologue: stage K0 + V0
    {
        const int Rr = l >> 3;
        const int sl = (l & 7) ^ Rr;
#pragma unroll
        for (int ss = 0; ss < 2; ++ss) {
            const int s = wid * 2 + ss;
            const int R = 8 * s + Rr;
            gload16(&kbf[(size_t)(kbeg + R) * 64 + sl * 8], lkb + s * 1024);
            gload16(&vtbf[(size_t)R * SEQ + kbeg + sl * 8], lvb + s * 1024);
        }
    }
    __syncthreads();

    floatx4 oacc[4];   // O^T[d = dt*16 + g*4 + r][q = wid*16 + q4]
#pragma unroll
    for (int i = 0; i < 4; ++i) oacc[i] = (floatx4){0.f, 0.f, 0.f, 0.f};
    floatx4 l_acc = (floatx4){0.f, 0.f, 0.f, 0.f};   // per-lane partial l
    float m_run = -INFINITY;

    int cur = 0;
    for (int tt = 0; tt < NT; ++tt) {
        const unsigned char* lk = lkb + cur * 8192;
        const unsigned char* lv = lvb + cur * 8192;

        // prefetch next K/V tile
        if (tt + 1 < NT) {
            const int kt1 = kbeg + (tt + 1) * 64;
            const int Rr = l >> 3;
            const int sl = (l & 7) ^ Rr;
#pragma unroll
            for (int ss = 0; ss < 2; ++ss) {
                const int s = wid * 2 + ss;
                const int R = 8 * s + Rr;
                gload16(&kbf[(size_t)(kt1 + R) * 64 + sl * 8],
                        lkb + (cur ^ 1) * 8192 + s * 1024);
                gload16(&vtbf[(size_t)R * SEQ + kt1 + sl * 8],
                        lvb + (cur ^ 1) * 8192 + s * 1024);
            }
        }

        // ---- S^T = K Q^T : sacc[nt][r] = S[q][key = nt*16 + g*4 + r] ----
        floatx4 sacc[4];
#pragma unroll
        for (int i = 0; i < 4; ++i) sacc[i] = (floatx4){0.f, 0.f, 0.f, 0.f};
#pragma unroll
        for (int ks = 0; ks < 2; ++ks) {
            const int sl = g + 4 * ks;
#pragma unroll
            for (int nt = 0; nt < 4; ++nt) {
                const int R = nt * 16 + q4;
                const short8 kf = *(const short8*)&lk[R * 128 + ((sl ^ (R & 7)) << 4)];
                sacc[nt] = __builtin_amdgcn_mfma_f32_16x16x32_bf16(kf, qf[ks], sacc[nt], 0, 0, 0);
            }
        }

        // ---- lane-local max; cross-lane only when rescale needed (rare) ----
        const floatx4 mm = max4(max4(sacc[0], sacc[1]), max4(sacc[2], sacc[3]));
        const float own = fmaxf(fmaxf(mm[0], mm[1]), fmaxf(mm[2], mm[3]));

        if (__any(own > m_run + 8.0f)) {
            float pm = own;
            pm = fmaxf(pm, __shfl_xor(pm, 16));
            pm = fmaxf(pm, __shfl_xor(pm, 32));
            const float mn = fmaxf(m_run, pm);
            const float alpha = exp2r(m_run - mn);
            m_run = mn;
            l_acc *= alpha;
#pragma unroll
            for (int dt = 0; dt < 4; ++dt) oacc[dt] *= alpha;
        }

        // ---- p = 2^(s - m_run); per-lane l accumulation (no shfl) ----
        floatx4 pv4[4];
#pragma unroll
        for (int nt = 0; nt < 4; ++nt) {
            floatx4 d = sacc[nt];
            d[0] -= m_run; d[1] -= m_run; d[2] -= m_run; d[3] -= m_run;
            pv4[nt][0] = exp2r(d[0]); pv4[nt][1] = exp2r(d[1]);
            pv4[nt][2] = exp2r(d[2]); pv4[nt][3] = exp2r(d[3]);
        }
        l_acc += (pv4[0] + pv4[1]) + (pv4[2] + pv4[3]);

        // ---- O^T += V^T P^T (P in-register) ----
#pragma unroll
        for (int kb = 0; kb < 4; ++kb) {
            const unsigned p0 = pack2(pv4[kb][0], pv4[kb][1]);
            const unsigned p1 = pack2(pv4[kb][2], pv4[kb][3]);
            const short4v bfr = __builtin_bit_cast(short4v, (uint2v){p0, p1});
            const int sl = kb * 2 + (g >> 1);
#pragma unroll
            for (int dt = 0; dt < 4; ++dt) {
                const int R = dt * 16 + q4;
                const short4v a = *(const short4v*)&lv[R * 128 +
                    ((sl ^ (R & 7)) << 4) + ((g & 1) << 3)];
                oacc[dt] = mfma16(a, bfr, oacc[dt]);
            }
        }

        __syncthreads();   // dbuf swap
        cur ^= 1;
    }

    // ---- one-time cross-lane l reduction ----
    float l_run = (l_acc[0] + l_acc[1]) + (l_acc[2] + l_acc[3]);
    l_run += __shfl_xor(l_run, 16);
    l_run += __shfl_xor(l_run, 32);

    // ---- epilogue: O^T -> O via LDS transpose, coalesced stores ----
    float* trans = (float*)lds;   // [64][68] fp32 = 17408 B (kv buffers done)
    {
        const int qrow = wid * 16 + q4;
        const float sc = direct ? (1.0f / l_run) : 1.0f;
#pragma unroll
        for (int dt = 0; dt < 4; ++dt) {
            floatx4 v = oacc[dt] * sc;
            *(floatx4*)&trans[qrow * 68 + dt * 16 + g * 4] = v;
        }
        if (!direct && l < 16) {
            const size_t mrow = (size_t)split * SEQ + row0 + wid * 16 + l;
            ml[mrow * 2 + 0] = m_run;
            ml[mrow * 2 + 1] = l_run;
        }
    }
    __syncthreads();

    float* outbase = direct ? opart : opart + (size_t)split * SEQ * 64;
#pragma unroll
    for (int it = 0; it < 4; ++it) {
        const int row = it * 16 + (t >> 4);
        const floatx4 v = *(const floatx4*)&trans[row * 68 + (t & 15) * 4];
        *(floatx4*)&outbase[(size_t)(row0 + row) * 64 + (t & 15) * 4] = v;
    }
}

// ---------------------------------------------------------------------------
// Kernel 3: combine split partials (log-sum-exp merge, base-2), float4
// ---------------------------------------------------------------------------
__global__ __launch_bounds__(256) void combine_kernel(
    const float* __restrict__ opart, const float* __restrict__ ml,
    float* __restrict__ out, int nsplit)
{
    const int i4 = blockIdx.x * 256 + threadIdx.x;   // one float4 per thread
    if (i4 >= SEQ * DOUT / 4) return;
    const int row = (i4 * 4) >> 6;

    float M = -INFINITY;
    for (int s = 0; s < nsplit; ++s)
        M = fmaxf(M, ml[((size_t)s * SEQ + row) * 2]);

    float denom = 0.f;
    floatx4 acc = (floatx4){0.f, 0.f, 0.f, 0.f};
    for (int s = 0; s < nsplit; ++s) {
        const float w = exp2r(ml[((size_t)s * SEQ + row) * 2] - M);
        denom += ml[((size_t)s * SEQ + row) * 2 + 1] * w;
        const floatx4 v = *(const floatx4*)&opart[(size_t)s * SEQ * DOUT + i4 * 4];
        acc += v * w;
    }
    acc *= (1.0f / denom);
    *(floatx4*)&out[i4 * 4] = acc;
}

// ---------------------------------------------------------------------------
extern "C" void kernel_launch(void* const* d_in, const int* in_sizes, int n_in,
                              void* d_out, int out_size, void* d_ws, size_t ws_size,
                              hipStream_t stream)
{
    const float* x  = (const float*)d_in[0];
    const float* Wq = (const float*)d_in[1];
    const float* Wk = (const float*)d_in[2];
    const float* Wv = (const float*)d_in[3];
    float* out = (float*)d_out;
    unsigned char* ws = (unsigned char*)d_ws;

    const size_t wbf_b = (size_t)192 * DIN * 2;
    const size_t qkv_b = (size_t)SEQ * 64 * 2;
    size_t off = 0;
    unsigned short* wbf  = (unsigned short*)(ws + off); off += wbf_b;
    unsigned short* qbf  = (unsigned short*)(ws + off); off += qkv_b;
    unsigned short* kbf  = (unsigned short*)(ws + off); off += qkv_b;
    unsigned short* vtbf = (unsigned short*)(ws + off); off += qkv_b;

    const size_t per_split = (size_t)SEQ * 64 * 4 + (size_t)SEQ * 2 * 4;
    int nsplit = 0;
    if      (ws_size >= off + 8 * per_split) nsplit = 8;
    else if (ws_size >= off + 4 * per_split) nsplit = 4;
    else if (ws_size >= off + 2 * per_split) nsplit = 2;

    prep_w<<<72, 256, 0, stream>>>(Wq, Wk, Wv, wbf);
    qkv_mfma<<<SEQ / 32, 256, 0, stream>>>(x, wbf, qbf, kbf, vtbf);

    if (nsplit == 0) {
        flash_mfma<<<dim3(SEQ / 64, 1), 256, 0, stream>>>(
            qbf, kbf, vtbf, out, nullptr, 1, 1);
    } else {
        float* opart = (float*)(ws + off);
        float* mlp   = (float*)(ws + off + (size_t)nsplit * SEQ * 64 * 4);
        flash_mfma<<<dim3(SEQ / 64, nsplit), 256, 0, stream>>>(
            qbf, kbf, vtbf, opart, mlp, nsplit, 0);
        combine_kernel<<<(SEQ * DOUT / 4 + 255) / 256, 256, 0, stream>>>(
            opart, mlp, out, nsplit);
    }
}